// Round 2
// baseline (2628.492 us; speedup 1.0000x reference)
//
#include <hip/hip_runtime.h>
#include <stdint.h>

#define T_STEPS 256
#define B_DIM   64
#define MDIM    512
#define NROWS   (T_STEPS * B_DIM)   // 16384
#define KCAT    1024                // [inputs | emb_s]
#define NBIG    3072                // 4M (iou) + M (ctx) + M (wcs)
#define W2ROWS  2560                // 5 gates * 512
#define NBLK2   32                  // persistent phase-2 blocks
#define OUT_N   ((size_t)T_STEPS * B_DIM * MDIM)  // 8388608

typedef short v8s __attribute__((ext_vector_type(8)));
typedef float v4f __attribute__((ext_vector_type(4)));
typedef unsigned long long u64;

static __device__ __forceinline__ unsigned short f2bf(float f) {
    unsigned u = __builtin_bit_cast(unsigned, f);
    u += 0x7FFFu + ((u >> 16) & 1u);            // RNE
    return (unsigned short)(u >> 16);
}
static __device__ __forceinline__ float bf2f(unsigned short h) {
    unsigned u = ((unsigned)h) << 16;
    return __builtin_bit_cast(float, u);
}
static __device__ __forceinline__ float sigmoidf(float x) {
    return 1.0f / (1.0f + __expf(-x));
}

// ---------------- prepack kernels ----------------

__global__ void pack_xcat(const float* __restrict__ x, const float* __restrict__ s,
                          unsigned short* __restrict__ xcat) {
    int idx = blockIdx.x * blockDim.x + threadIdx.x;   // over NROWS*KCAT
    if (idx >= NROWS * KCAT) return;
    int row = idx >> 10, col = idx & 1023;
    float v = (col < 512) ? x[row * 512 + col] : s[row * 512 + (col - 512)];
    xcat[idx] = f2bf(v);
}

__global__ void pack_wbig(const float* __restrict__ Wioux, const float* __restrict__ bioux,
                          const float* __restrict__ Wious, const float* __restrict__ bious,
                          const float* __restrict__ Wfx,   const float* __restrict__ bfx,
                          const float* __restrict__ Wwc,   const float* __restrict__ bwc,
                          unsigned short* __restrict__ wbig, float* __restrict__ bbig) {
    int idx = blockIdx.x * blockDim.x + threadIdx.x;   // over NBIG*KCAT
    if (idx >= NBIG * KCAT) return;
    int r = idx >> 10, c = idx & 1023;
    float v;
    if (r < 2048)      v = (c < 512) ? Wioux[r * 512 + c] : Wious[r * 512 + (c - 512)];
    else if (r < 2560) { int j = r - 2048; v = (c < 512) ? Wfx[j * 512 + c] : 0.0f; }
    else               { int j = r - 2560; v = (c < 512) ? 0.0f : Wwc[j * 512 + (c - 512)]; }
    wbig[idx] = f2bf(v);
    if (c == 0) {
        float b;
        if (r < 2048)      b = bioux[r] + bious[r];
        else if (r < 2560) b = bfx[r - 2048];
        else               b = bwc[r - 2560];
        bbig[r] = b;
    }
}

// Pack recurrent weights: block bk owns m-cols [16*bk,16*bk+16):
// 5 n-tiles of 16 rows: g=0..3 -> W_iouh rows g*512+m ; g=4 -> W_fh row m
__global__ void pack_w2(const float* __restrict__ Wiouh, const float* __restrict__ biouh,
                        const float* __restrict__ Wfh,   const float* __restrict__ bfh,
                        unsigned short* __restrict__ w2, float* __restrict__ b2) {
    int idx = blockIdx.x * blockDim.x + threadIdx.x;   // over W2ROWS*512
    if (idx >= W2ROWS * 512) return;
    int r = idx >> 9, k = idx & 511;
    int bk = r / 80, rem = r % 80, g = rem >> 4, j = rem & 15;
    int m = bk * 16 + j;
    float v, bias;
    if (g < 4) { v = Wiouh[(size_t)(g * 512 + m) * 512 + k]; bias = biouh[g * 512 + m]; }
    else       { v = Wfh[(size_t)m * 512 + k];               bias = bfh[m]; }
    w2[idx] = f2bf(v);
    if (k == 0) b2[r] = bias;
}

// h state layout: [slice = col>>4][64 rows][16 cols] bf16 so each phase-2 block's
// slice (its 16 m-cols) is one contiguous 2 KB slab -> 8B coherent stores/loads.
__global__ void init_state(const float* __restrict__ h0,
                           unsigned short* __restrict__ hslab0,
                           int* __restrict__ flags) {
    int idx = blockIdx.x * blockDim.x + threadIdx.x;   // 32768
    if (idx < NBLK2) flags[idx] = 0;
    if (idx >= B_DIM * MDIM) return;
    int row = idx >> 9, col = idx & 511;
    hslab0[((col >> 4) * 64 + row) * 16 + (col & 15)] = f2bf(h0[idx]);
}

// ---------------- phase 1: big GEMM, output pre-swizzled into per-(t,block) slabs ----------------
// ytile layout: [T][32 bk][64 b][6 slot][16 col] bf16 ; slot 0..3 = iou gates, 4 = ctx, 5 = wcs(tanh).
// Each (t,bk) slab is 12 KB contiguous == exactly what one phase-2 block prefetches per step.

__global__ __launch_bounds__(256) void gemm_big(
        const unsigned short* __restrict__ xcat,
        const unsigned short* __restrict__ wbig,
        const float* __restrict__ bbig,
        unsigned short* __restrict__ ytile) {
    __shared__ __align__(16) unsigned short As[128][40];
    __shared__ __align__(16) unsigned short Bs[128][40];
    int nb = blockIdx.x;              // 0..23 (col block)
    int mb = blockIdx.y;              // 0..127 (row block)
    int tid = threadIdx.x;
    int lane = tid & 63, wid = tid >> 6;
    int wm = wid & 1, wn = wid >> 1;  // 2x2 wave grid, each wave 64x64
    int lm = lane & 15, lq = lane >> 4;
    v4f acc[4][4] = {};
    for (int kb = 0; kb < KCAT / 32; ++kb) {
        __syncthreads();
        #pragma unroll
        for (int it = 0; it < 2; ++it) {
            int cid = tid + it * 256;
            int r = cid >> 2, q = cid & 3;
            *(uint4*)&As[r][q * 8] =
                *(const uint4*)(xcat + (size_t)(mb * 128 + r) * KCAT + kb * 32 + q * 8);
            *(uint4*)&Bs[r][q * 8] =
                *(const uint4*)(wbig + (size_t)(nb * 128 + r) * KCAT + kb * 32 + q * 8);
        }
        __syncthreads();
        v8s a[4], b[4];
        #pragma unroll
        for (int i = 0; i < 4; ++i) a[i] = *(const v8s*)&As[wm * 64 + i * 16 + lm][lq * 8];
        #pragma unroll
        for (int j = 0; j < 4; ++j) b[j] = *(const v8s*)&Bs[wn * 64 + j * 16 + lm][lq * 8];
        #pragma unroll
        for (int i = 0; i < 4; ++i)
            #pragma unroll
            for (int j = 0; j < 4; ++j)
                acc[i][j] = __builtin_amdgcn_mfma_f32_16x16x32_bf16(a[i], b[j], acc[i][j], 0, 0, 0);
    }
    int tt = mb * 2 + wm;                     // time index of this wave's 64 rows
    #pragma unroll
    for (int i = 0; i < 4; ++i) {
        int rbase = i * 16 + lq * 4;          // batch row base (0..60)
        #pragma unroll
        for (int j = 0; j < 4; ++j) {
            int gn = nb * 128 + wn * 64 + j * 16 + lm;
            float bias = bbig[gn];
            bool do_tanh = (gn >= 2560);
            int slot, mcol;
            if (gn < 2048)      { slot = gn >> 9; mcol = gn & 511; }
            else if (gn < 2560) { slot = 4; mcol = gn - 2048; }
            else                { slot = 5; mcol = gn - 2560; }
            size_t base = ((((size_t)tt * NBLK2 + (mcol >> 4)) * 64 + rbase) * 6 + slot) * 16
                          + (mcol & 15);
            #pragma unroll
            for (int r = 0; r < 4; ++r) {
                float v = acc[i][j][r] + bias;
                if (do_tanh) v = tanhf(v);
                ytile[base + (size_t)r * 96] = f2bf(v);
            }
        }
    }
}

// ---------------- phase 2: persistent kernel, flag-based sync (no heavyweight fences) ----------------
// 32 blocks x 256 threads; block bk owns m-cols [16bk,16bk+16).
// Cross-XCD h exchange uses AGENT-scope *relaxed* atomic 8B accesses (point-coherent at IF,
// no per-step L2 writeback/invalidate). Per-block readiness flags replace the counter barrier:
//   producer: h stores (sc1) -> s_waitcnt vmcnt(0) -> flag[bk] = t+1
//   consumer: poll all 32 flags (one coalesced vector load) >= t, then sc1 h loads.
// WAR safety: flag(t+1) set only after this block's reads of h(t) completed (program order),
// so a block writing buffer X at step t+1 cannot clobber data still being read at step t.

__global__ __launch_bounds__(256, 1) void lstm_persist(
        const unsigned short* __restrict__ ytile,
        const unsigned short* __restrict__ w2,
        const float* __restrict__ b2,
        const float* __restrict__ c0,
        unsigned short* hslab0,
        unsigned short* hslab1,
        float* __restrict__ out,
        int* __restrict__ flags) {
    __shared__ __align__(16) float red[2][10][256];              // 20 KB: K-partials
    __shared__ __align__(16) unsigned short ybuf[2][6144];       // 24 KB: y slabs (dbuf)
    __shared__ __align__(16) unsigned short hstage[64][16];      // 2 KB: h slice assembly
    int bk = blockIdx.x;
    int tid = threadIdx.x;
    int lane = tid & 63, wid = tid >> 6;
    int p = wid >> 1;                 // batch half
    int q = wid & 1;                  // K half
    int lm = lane & 15, lq = lane >> 4;
    int m = bk * 16 + lm;

    // B fragments in registers: gate g, kk = q*8+j
    v8s bfrag[5][8];
    const unsigned short* w2b = w2 + (size_t)(bk * 80 + lm) * 512 + lq * 8;
    #pragma unroll
    for (int g = 0; g < 5; ++g)
        #pragma unroll
        for (int j = 0; j < 8; ++j)
            bfrag[g][j] = *(const v8s*)(w2b + (size_t)g * 16 * 512 + (q * 8 + j) * 32);

    // biases + c state (used by q==0 epilogue waves)
    float bias[5];
    #pragma unroll
    for (int g = 0; g < 5; ++g) bias[g] = b2[(bk * 5 + g) * 16 + lm];
    float creg[2][4];
    #pragma unroll
    for (int tb = 0; tb < 2; ++tb)
        #pragma unroll
        for (int r = 0; r < 4; ++r)
            creg[tb][r] = c0[(p * 32 + tb * 16 + lq * 4 + r) * 512 + m];

    // initial y prefetch (t=0 -> buf 0) by q==1 waves: 6 x 1KB coalesced chunks per wave
    if (q == 1) {
        const unsigned short* slab = ytile + (size_t)bk * 6144;
        #pragma unroll
        for (int i = 0; i < 6; ++i) {
            int ch = p * 6 + i;
            __builtin_amdgcn_global_load_lds(
                (const __attribute__((address_space(1))) unsigned int*)(slab + ch * 512 + lane * 8),
                (__attribute__((address_space(3))) unsigned int*)(&ybuf[0][0] + ch * 512), 16, 0, 0);
        }
    }

    for (int t = 0; t < T_STEPS; ++t) {
        int cur = t & 1;
        // (1) issue next y-slab prefetch FIRST so its HBM latency overlaps the flag wait
        if (q == 1 && t + 1 < T_STEPS) {
            const unsigned short* slab = ytile + (size_t)((t + 1) * NBLK2 + bk) * 6144;
            unsigned short* lbase = &ybuf[cur ^ 1][0];
            #pragma unroll
            for (int i = 0; i < 6; ++i) {
                int ch = p * 6 + i;
                __builtin_amdgcn_global_load_lds(
                    (const __attribute__((address_space(1))) unsigned int*)(slab + ch * 512 + lane * 8),
                    (__attribute__((address_space(3))) unsigned int*)(lbase + ch * 512), 16, 0, 0);
            }
        }
        // (2) wait until every block has published h(t)
        if (t) {
            int slot = lane & 31;
            while (!__all(__hip_atomic_load(flags + slot, __ATOMIC_RELAXED,
                                            __HIP_MEMORY_SCOPE_AGENT) >= t)) {}
            asm volatile("" ::: "memory");
        }
        // (3) batched coherent h loads (issued back-to-back, then consumed by MFMA chain)
        const u64* hin = cur ? (const u64*)hslab1 : (const u64*)hslab0;
        u64*       hnx = cur ? (u64*)hslab0 : (u64*)hslab1;
        u64 hq[32];
        {
            const u64* hb = hin + ((size_t)(q * 16 + (lq >> 1)) * 64 + p * 32 + lm) * 4
                          + (lq & 1) * 2;
            #pragma unroll
            for (int j = 0; j < 8; ++j) {
                hq[j * 4 + 0] = __hip_atomic_load(hb + j * 512,      __ATOMIC_RELAXED, __HIP_MEMORY_SCOPE_AGENT);
                hq[j * 4 + 1] = __hip_atomic_load(hb + j * 512 + 1,  __ATOMIC_RELAXED, __HIP_MEMORY_SCOPE_AGENT);
                hq[j * 4 + 2] = __hip_atomic_load(hb + j * 512 + 64, __ATOMIC_RELAXED, __HIP_MEMORY_SCOPE_AGENT);
                hq[j * 4 + 3] = __hip_atomic_load(hb + j * 512 + 65, __ATOMIC_RELAXED, __HIP_MEMORY_SCOPE_AGENT);
            }
        }
        v4f acc[2][5] = {};
        #pragma unroll
        for (int j = 0; j < 8; ++j) {
            union { u64 qq[2]; v8s v; } a0, a1;
            a0.qq[0] = hq[j * 4 + 0]; a0.qq[1] = hq[j * 4 + 1];
            a1.qq[0] = hq[j * 4 + 2]; a1.qq[1] = hq[j * 4 + 3];
            #pragma unroll
            for (int g = 0; g < 5; ++g) {
                acc[0][g] = __builtin_amdgcn_mfma_f32_16x16x32_bf16(a0.v, bfrag[g][j], acc[0][g], 0, 0, 0);
                acc[1][g] = __builtin_amdgcn_mfma_f32_16x16x32_bf16(a1.v, bfrag[g][j], acc[1][g], 0, 0, 0);
            }
        }
        if (q == 1) {   // publish K-partials
            #pragma unroll
            for (int tb = 0; tb < 2; ++tb)
                #pragma unroll
                for (int g = 0; g < 5; ++g)
                    *(v4f*)&red[p][tb * 5 + g][lane * 4] = acc[tb][g];
        }
        __syncthreads();                                   // S1
        if (q == 0) {   // reduce + epilogue (identical arithmetic to baseline)
            #pragma unroll
            for (int tb = 0; tb < 2; ++tb)
                #pragma unroll
                for (int g = 0; g < 5; ++g)
                    acc[tb][g] += *(const v4f*)&red[p][tb * 5 + g][lane * 4];
            const unsigned short* yb = &ybuf[cur][0];
            #pragma unroll
            for (int tb = 0; tb < 2; ++tb) {
                #pragma unroll
                for (int r = 0; r < 4; ++r) {
                    int brow = p * 32 + tb * 16 + lq * 4 + r;
                    const unsigned short* ybr = yb + brow * 96;
                    float f_ = sigmoidf(bf2f(ybr[0 * 16 + lm]) + acc[tb][0][r] + bias[0]);
                    float i_ = sigmoidf(bf2f(ybr[1 * 16 + lm]) + acc[tb][1][r] + bias[1]);
                    float o_ = sigmoidf(bf2f(ybr[2 * 16 + lm]) + acc[tb][2][r] + bias[2]);
                    float oc = sigmoidf(bf2f(ybr[3 * 16 + lm]) + acc[tb][3][r] + bias[3]);
                    float ct = tanhf  (bf2f(ybr[4 * 16 + lm]) + acc[tb][4][r] + bias[4]);
                    float wcs = bf2f(ybr[5 * 16 + lm]);
                    float cn = i_ * ct + f_ * creg[tb][r];
                    creg[tb][r] = cn;
                    float hn = o_ * tanhf(cn) + oc * wcs;
                    out[((size_t)t * 64 + brow) * 512 + m] = hn;
                    hstage[brow][lm] = f2bf(hn);
                    if (t == T_STEPS - 1)
                        out[OUT_N + 32768 + (size_t)brow * 512 + m] = hn;   // h_fin
                }
            }
        }
        __syncthreads();                                   // S2
        // (4) wave 0 publishes this block's 2KB h slice + readiness flag.
        //     Slab stride is 256 u64 (64 rows * 4 u64/row).  [round-1 bug: was bk*128]
        if (wid == 0) {
            const u64* hsl = (const u64*)&hstage[0][0];
            u64* dst = hnx + (size_t)bk * 256;
            u64 x0 = hsl[lane * 4 + 0], x1 = hsl[lane * 4 + 1];
            u64 x2 = hsl[lane * 4 + 2], x3 = hsl[lane * 4 + 3];
            __hip_atomic_store(dst + lane * 4 + 0, x0, __ATOMIC_RELAXED, __HIP_MEMORY_SCOPE_AGENT);
            __hip_atomic_store(dst + lane * 4 + 1, x1, __ATOMIC_RELAXED, __HIP_MEMORY_SCOPE_AGENT);
            __hip_atomic_store(dst + lane * 4 + 2, x2, __ATOMIC_RELAXED, __HIP_MEMORY_SCOPE_AGENT);
            __hip_atomic_store(dst + lane * 4 + 3, x3, __ATOMIC_RELAXED, __HIP_MEMORY_SCOPE_AGENT);
            asm volatile("s_waitcnt vmcnt(0)" ::: "memory");
            if (lane == 0 && t + 1 < T_STEPS)
                __hip_atomic_store(flags + bk, t + 1, __ATOMIC_RELAXED, __HIP_MEMORY_SCOPE_AGENT);
        }
    }

    // c_fin
    if (q == 0) {
        #pragma unroll
        for (int tb = 0; tb < 2; ++tb)
            #pragma unroll
            for (int r = 0; r < 4; ++r)
                out[OUT_N + (size_t)(p * 32 + tb * 16 + lq * 4 + r) * 512 + m] = creg[tb][r];
    }
}

// ---------------- launch ----------------

extern "C" void kernel_launch(void* const* d_in, const int* in_sizes, int n_in,
                              void* d_out, int out_size, void* d_ws, size_t ws_size,
                              hipStream_t stream) {
    const float* inputs = (const float*)d_in[0];
    const float* emb_s  = (const float*)d_in[1];
    const float* c0     = (const float*)d_in[2];
    const float* h0     = (const float*)d_in[3];
    const float* W_ioux = (const float*)d_in[4];  const float* b_ioux = (const float*)d_in[5];
    const float* W_iouh = (const float*)d_in[6];  const float* b_iouh = (const float*)d_in[7];
    const float* W_ious = (const float*)d_in[8];  const float* b_ious = (const float*)d_in[9];
    const float* W_fx   = (const float*)d_in[10]; const float* b_fx   = (const float*)d_in[11];
    const float* W_fh   = (const float*)d_in[12]; const float* b_fh   = (const float*)d_in[13];
    const float* W_wc   = (const float*)d_in[14]; const float* b_wc   = (const float*)d_in[15];
    float* out = (float*)d_out;

    char* ws = (char*)d_ws;
    size_t off = 0;
    auto alloc = [&](size_t bytes) -> void* {
        void* p = ws + off;
        off += (bytes + 255) & ~(size_t)255;
        return p;
    };
    unsigned short* ytile = (unsigned short*)alloc((size_t)NROWS * NBIG * 2);   // 100.7 MB
    unsigned short* xcat  = (unsigned short*)alloc((size_t)NROWS * KCAT * 2);   // 33.6 MB
    unsigned short* wbig  = (unsigned short*)alloc((size_t)NBIG * KCAT * 2);    // 6.3 MB
    float*          bbig  = (float*)alloc(NBIG * 4);
    unsigned short* w2    = (unsigned short*)alloc((size_t)W2ROWS * 512 * 2);   // 2.6 MB
    float*          b2    = (float*)alloc(W2ROWS * 4);
    unsigned short* hslab0 = (unsigned short*)alloc(B_DIM * MDIM * 2);
    unsigned short* hslab1 = (unsigned short*)alloc(B_DIM * MDIM * 2);
    int*            flags  = (int*)alloc(256);

    pack_xcat<<<(NROWS * KCAT + 255) / 256, 256, 0, stream>>>(inputs, emb_s, xcat);
    pack_wbig<<<(NBIG * KCAT + 255) / 256, 256, 0, stream>>>(
        W_ioux, b_ioux, W_ious, b_ious, W_fx, b_fx, W_wc, b_wc, wbig, bbig);
    pack_w2<<<(W2ROWS * 512 + 255) / 256, 256, 0, stream>>>(W_iouh, b_iouh, W_fh, b_fh, w2, b2);
    init_state<<<(B_DIM * MDIM + 255) / 256, 256, 0, stream>>>(h0, hslab0, flags);

    dim3 g1(NBIG / 128, NROWS / 128);
    gemm_big<<<g1, 256, 0, stream>>>(xcat, wbig, bbig, ytile);

    lstm_persist<<<NBLK2, 256, 0, stream>>>(ytile, w2, b2, c0, hslab0, hslab1, out, flags);
}

// Round 3
// 1883.979 us; speedup vs baseline: 1.3952x; 1.3952x over previous
//
#include <hip/hip_runtime.h>
#include <stdint.h>

#define T_STEPS 256
#define B_DIM   64
#define MDIM    512
#define NROWS   (T_STEPS * B_DIM)   // 16384
#define KCAT    1024                // [inputs | emb_s]
#define NBIG    3072                // 4M (iou) + M (ctx) + M (wcs)
#define W2ROWS  2560                // 5 gates * 512
#define NBLK2   32                  // persistent phase-2 blocks
#define OUT_N   ((size_t)T_STEPS * B_DIM * MDIM)  // 8388608

typedef short v8s __attribute__((ext_vector_type(8)));
typedef float v4f __attribute__((ext_vector_type(4)));
typedef unsigned long long u64;

static __device__ __forceinline__ unsigned short f2bf(float f) {
    unsigned u = __builtin_bit_cast(unsigned, f);
    u += 0x7FFFu + ((u >> 16) & 1u);            // RNE
    return (unsigned short)(u >> 16);
}
static __device__ __forceinline__ float bf2f(unsigned short h) {
    unsigned u = ((unsigned)h) << 16;
    return __builtin_bit_cast(float, u);
}
// fast transcendentals: v_rcp (~1ulp) + v_exp; error ~1e-6 rel, far below the
// 3e-3/step bf16 h-quantization already in this pipeline (absmax 0.020 vs thr 0.057)
static __device__ __forceinline__ float fast_rcp(float x) {
    return __builtin_amdgcn_rcpf(x);
}
static __device__ __forceinline__ float sigmoid_fast(float x) {
    return fast_rcp(1.0f + __expf(-x));
}
static __device__ __forceinline__ float tanh_fast(float x) {
    // tanh(x) = 1 - 2/(1+e^{2x}) ; saturates correctly for |x| large
    return 1.0f - 2.0f * fast_rcp(1.0f + __expf(2.0f * x));
}

// ---------------- prepack kernels ----------------

__global__ void pack_xcat(const float* __restrict__ x, const float* __restrict__ s,
                          unsigned short* __restrict__ xcat) {
    int idx = blockIdx.x * blockDim.x + threadIdx.x;   // over NROWS*KCAT
    if (idx >= NROWS * KCAT) return;
    int row = idx >> 10, col = idx & 1023;
    float v = (col < 512) ? x[row * 512 + col] : s[row * 512 + (col - 512)];
    xcat[idx] = f2bf(v);
}

__global__ void pack_wbig(const float* __restrict__ Wioux, const float* __restrict__ bioux,
                          const float* __restrict__ Wious, const float* __restrict__ bious,
                          const float* __restrict__ Wfx,   const float* __restrict__ bfx,
                          const float* __restrict__ Wwc,   const float* __restrict__ bwc,
                          unsigned short* __restrict__ wbig, float* __restrict__ bbig) {
    int idx = blockIdx.x * blockDim.x + threadIdx.x;   // over NBIG*KCAT
    if (idx >= NBIG * KCAT) return;
    int r = idx >> 10, c = idx & 1023;
    float v;
    if (r < 2048)      v = (c < 512) ? Wioux[r * 512 + c] : Wious[r * 512 + (c - 512)];
    else if (r < 2560) { int j = r - 2048; v = (c < 512) ? Wfx[j * 512 + c] : 0.0f; }
    else               { int j = r - 2560; v = (c < 512) ? 0.0f : Wwc[j * 512 + (c - 512)]; }
    wbig[idx] = f2bf(v);
    if (c == 0) {
        float b;
        if (r < 2048)      b = bioux[r] + bious[r];
        else if (r < 2560) b = bfx[r - 2048];
        else               b = bwc[r - 2560];
        bbig[r] = b;
    }
}

// Pack recurrent weights: block bk owns m-cols [16*bk,16*bk+16):
// 5 n-tiles of 16 rows: g=0..3 -> W_iouh rows g*512+m ; g=4 -> W_fh row m
__global__ void pack_w2(const float* __restrict__ Wiouh, const float* __restrict__ biouh,
                        const float* __restrict__ Wfh,   const float* __restrict__ bfh,
                        unsigned short* __restrict__ w2, float* __restrict__ b2) {
    int idx = blockIdx.x * blockDim.x + threadIdx.x;   // over W2ROWS*512
    if (idx >= W2ROWS * 512) return;
    int r = idx >> 9, k = idx & 511;
    int bk = r / 80, rem = r % 80, g = rem >> 4, j = rem & 15;
    int m = bk * 16 + j;
    float v, bias;
    if (g < 4) { v = Wiouh[(size_t)(g * 512 + m) * 512 + k]; bias = biouh[g * 512 + m]; }
    else       { v = Wfh[(size_t)m * 512 + k];               bias = bfh[m]; }
    w2[idx] = f2bf(v);
    if (k == 0) b2[r] = bias;
}

// h state layout: [slice = col>>4][64 rows][16 cols] bf16 so each phase-2 block's
// slice (its 16 m-cols) is one contiguous 2 KB slab.
// flags: 64 producer flags (one per q==0 wave), each on its OWN 128B line to
// distribute poll traffic across LLC banks (v2 lesson: one hot line self-throttles).
__global__ void init_state(const float* __restrict__ h0,
                           unsigned short* __restrict__ hslab0,
                           int* __restrict__ flags) {
    int idx = blockIdx.x * blockDim.x + threadIdx.x;   // 32768
    if (idx < 2048) flags[idx] = 0;                    // 64 flags * 32-int stride
    if (idx >= B_DIM * MDIM) return;
    int row = idx >> 9, col = idx & 511;
    hslab0[((col >> 4) * 64 + row) * 16 + (col & 15)] = f2bf(h0[idx]);
}

// ---------------- phase 1: big GEMM, output pre-swizzled into per-(t,block) slabs ----------------
// ytile layout: [T][32 bk][64 b][6 slot][16 col] bf16 ; slot 0..3 = iou gates, 4 = ctx, 5 = wcs(tanh).
// Each (t,bk) slab is 12 KB contiguous == exactly what one phase-2 block prefetches per step.

__global__ __launch_bounds__(256) void gemm_big(
        const unsigned short* __restrict__ xcat,
        const unsigned short* __restrict__ wbig,
        const float* __restrict__ bbig,
        unsigned short* __restrict__ ytile) {
    __shared__ __align__(16) unsigned short As[128][40];
    __shared__ __align__(16) unsigned short Bs[128][40];
    int nb = blockIdx.x;              // 0..23 (col block)
    int mb = blockIdx.y;              // 0..127 (row block)
    int tid = threadIdx.x;
    int lane = tid & 63, wid = tid >> 6;
    int wm = wid & 1, wn = wid >> 1;  // 2x2 wave grid, each wave 64x64
    int lm = lane & 15, lq = lane >> 4;
    v4f acc[4][4] = {};
    for (int kb = 0; kb < KCAT / 32; ++kb) {
        __syncthreads();
        #pragma unroll
        for (int it = 0; it < 2; ++it) {
            int cid = tid + it * 256;
            int r = cid >> 2, q = cid & 3;
            *(uint4*)&As[r][q * 8] =
                *(const uint4*)(xcat + (size_t)(mb * 128 + r) * KCAT + kb * 32 + q * 8);
            *(uint4*)&Bs[r][q * 8] =
                *(const uint4*)(wbig + (size_t)(nb * 128 + r) * KCAT + kb * 32 + q * 8);
        }
        __syncthreads();
        v8s a[4], b[4];
        #pragma unroll
        for (int i = 0; i < 4; ++i) a[i] = *(const v8s*)&As[wm * 64 + i * 16 + lm][lq * 8];
        #pragma unroll
        for (int j = 0; j < 4; ++j) b[j] = *(const v8s*)&Bs[wn * 64 + j * 16 + lm][lq * 8];
        #pragma unroll
        for (int i = 0; i < 4; ++i)
            #pragma unroll
            for (int j = 0; j < 4; ++j)
                acc[i][j] = __builtin_amdgcn_mfma_f32_16x16x32_bf16(a[i], b[j], acc[i][j], 0, 0, 0);
    }
    int tt = mb * 2 + wm;                     // time index of this wave's 64 rows
    #pragma unroll
    for (int i = 0; i < 4; ++i) {
        int rbase = i * 16 + lq * 4;          // batch row base (0..60)
        #pragma unroll
        for (int j = 0; j < 4; ++j) {
            int gn = nb * 128 + wn * 64 + j * 16 + lm;
            float bias = bbig[gn];
            bool do_tanh = (gn >= 2560);
            int slot, mcol;
            if (gn < 2048)      { slot = gn >> 9; mcol = gn & 511; }
            else if (gn < 2560) { slot = 4; mcol = gn - 2048; }
            else                { slot = 5; mcol = gn - 2560; }
            size_t base = ((((size_t)tt * NBLK2 + (mcol >> 4)) * 64 + rbase) * 6 + slot) * 16
                          + (mcol & 15);
            #pragma unroll
            for (int r = 0; r < 4; ++r) {
                float v = acc[i][j][r] + bias;
                if (do_tanh) v = tanhf(v);
                ytile[base + (size_t)r * 96] = f2bf(v);
            }
        }
    }
}

// ---------------- phase 2: persistent kernel ----------------
// 32 blocks x 256 threads; block bk owns m-cols [16bk,16bk+16).
// Sync per step (v3):
//   producer (each q==0 wave): compute h -> pair-pack -> 4B sc1 stores (own 32 rows
//     x 16 cols) -> vmcnt(0) -> own flag (own 128B line) = t+1 -> then out stores.
//   consumer: ONE wave per block (wid 1) polls all 64 flags (each lane one flag,
//     stride 128B -> spread over LLC banks), then __syncthreads releases the block.
// Ordering proofs:
//   red WAR:  q==1 writes red(t+1) after S0(t+1), which q==0 passes only after
//             finishing epilogue(t) (red reads done).
//   ybuf WAR: prefetch(t+1) at bottom of t targets buf[(t+1)&1]; epilogue(t) reads
//             buf[t&1]; next overwrite of a buffer is 2 steps later, past S0/S1.
//   hslab WAR: write of buf X at t+1 gated on all flags>=t+1; flag(t+1) of block B
//             is set after B's S1(t), which B's q==1 reaches only after its MFMA
//             consumed the h(t) loads.
//   ybuf completion: gload_lds issued at bottom of t-1 precedes hq loads of t in
//             vmcnt order; MFMA's wait on hq drains the prefetch before S1(t).

__global__ __launch_bounds__(256, 1) void lstm_persist(
        const unsigned short* __restrict__ ytile,
        const unsigned short* __restrict__ w2,
        const float* __restrict__ b2,
        const float* __restrict__ c0,
        unsigned short* hslab0,
        unsigned short* hslab1,
        float* __restrict__ out,
        int* __restrict__ flags) {
    __shared__ __align__(16) float red[2][10][256];              // 20 KB: K-partials
    __shared__ __align__(16) unsigned short ybuf[2][6144];       // 24 KB: y slabs (dbuf)
    int bk = blockIdx.x;
    int tid = threadIdx.x;
    int lane = tid & 63, wid = tid >> 6;
    int p = wid >> 1;                 // batch half
    int q = wid & 1;                  // K half
    int lm = lane & 15, lq = lane >> 4;
    int m = bk * 16 + lm;

    // B fragments in registers: gate g, kk = q*8+j
    v8s bfrag[5][8];
    const unsigned short* w2b = w2 + (size_t)(bk * 80 + lm) * 512 + lq * 8;
    #pragma unroll
    for (int g = 0; g < 5; ++g)
        #pragma unroll
        for (int j = 0; j < 8; ++j)
            bfrag[g][j] = *(const v8s*)(w2b + (size_t)g * 16 * 512 + (q * 8 + j) * 32);

    // biases + c state (used by q==0 epilogue waves)
    float bias[5];
    #pragma unroll
    for (int g = 0; g < 5; ++g) bias[g] = b2[(bk * 5 + g) * 16 + lm];
    float creg[2][4];
    #pragma unroll
    for (int tb = 0; tb < 2; ++tb)
        #pragma unroll
        for (int r = 0; r < 4; ++r)
            creg[tb][r] = c0[(p * 32 + tb * 16 + lq * 4 + r) * 512 + m];

    // initial y prefetch (t=0 -> buf 0) by q==1 waves: 6 x 1KB coalesced chunks per wave
    if (q == 1) {
        const unsigned short* slab = ytile + (size_t)bk * 6144;
        #pragma unroll
        for (int i = 0; i < 6; ++i) {
            int ch = p * 6 + i;
            __builtin_amdgcn_global_load_lds(
                (const __attribute__((address_space(1))) unsigned int*)(slab + ch * 512 + lane * 8),
                (__attribute__((address_space(3))) unsigned int*)(&ybuf[0][0] + ch * 512), 16, 0, 0);
        }
    }

    for (int t = 0; t < T_STEPS; ++t) {
        int cur = t & 1;
        // (1) wait until every producer wave has published h(t): single-poller + barrier
        if (t) {
            if (wid == 1)
                while (!__all(__hip_atomic_load(flags + lane * 32, __ATOMIC_RELAXED,
                                                __HIP_MEMORY_SCOPE_AGENT) >= t)) {}
            __syncthreads();                               // S0: release block
            asm volatile("" ::: "memory");
        }
        // (2) batched coherent h loads (issued back-to-back, consumed by MFMA chain)
        const u64* hin = cur ? (const u64*)hslab1 : (const u64*)hslab0;
        unsigned*  hnx = cur ? (unsigned*)hslab0 : (unsigned*)hslab1;
        u64 hq[32];
        {
            const u64* hb = hin + ((size_t)(q * 16 + (lq >> 1)) * 64 + p * 32 + lm) * 4
                          + (lq & 1) * 2;
            #pragma unroll
            for (int j = 0; j < 8; ++j) {
                hq[j * 4 + 0] = __hip_atomic_load(hb + j * 512,      __ATOMIC_RELAXED, __HIP_MEMORY_SCOPE_AGENT);
                hq[j * 4 + 1] = __hip_atomic_load(hb + j * 512 + 1,  __ATOMIC_RELAXED, __HIP_MEMORY_SCOPE_AGENT);
                hq[j * 4 + 2] = __hip_atomic_load(hb + j * 512 + 64, __ATOMIC_RELAXED, __HIP_MEMORY_SCOPE_AGENT);
                hq[j * 4 + 3] = __hip_atomic_load(hb + j * 512 + 65, __ATOMIC_RELAXED, __HIP_MEMORY_SCOPE_AGENT);
            }
        }
        v4f acc[2][5] = {};
        #pragma unroll
        for (int j = 0; j < 8; ++j) {
            union { u64 qq[2]; v8s v; } a0, a1;
            a0.qq[0] = hq[j * 4 + 0]; a0.qq[1] = hq[j * 4 + 1];
            a1.qq[0] = hq[j * 4 + 2]; a1.qq[1] = hq[j * 4 + 3];
            #pragma unroll
            for (int g = 0; g < 5; ++g) {
                acc[0][g] = __builtin_amdgcn_mfma_f32_16x16x32_bf16(a0.v, bfrag[g][j], acc[0][g], 0, 0, 0);
                acc[1][g] = __builtin_amdgcn_mfma_f32_16x16x32_bf16(a1.v, bfrag[g][j], acc[1][g], 0, 0, 0);
            }
        }
        if (q == 1) {   // publish K-partials
            #pragma unroll
            for (int tb = 0; tb < 2; ++tb)
                #pragma unroll
                for (int g = 0; g < 5; ++g)
                    *(v4f*)&red[p][tb * 5 + g][lane * 4] = acc[tb][g];
        }
        __syncthreads();                                   // S1
        if (q == 0) {   // reduce + epilogue + direct h publish
            #pragma unroll
            for (int tb = 0; tb < 2; ++tb)
                #pragma unroll
                for (int g = 0; g < 5; ++g)
                    acc[tb][g] += *(const v4f*)&red[p][tb * 5 + g][lane * 4];
            const unsigned short* yb = &ybuf[cur][0];
            float hnv[2][4];
            unsigned hbf[2][4];
            #pragma unroll
            for (int tb = 0; tb < 2; ++tb) {
                #pragma unroll
                for (int r = 0; r < 4; ++r) {
                    int brow = p * 32 + tb * 16 + lq * 4 + r;
                    const unsigned short* ybr = yb + brow * 96;
                    float f_ = sigmoid_fast(bf2f(ybr[0 * 16 + lm]) + acc[tb][0][r] + bias[0]);
                    float i_ = sigmoid_fast(bf2f(ybr[1 * 16 + lm]) + acc[tb][1][r] + bias[1]);
                    float o_ = sigmoid_fast(bf2f(ybr[2 * 16 + lm]) + acc[tb][2][r] + bias[2]);
                    float oc = sigmoid_fast(bf2f(ybr[3 * 16 + lm]) + acc[tb][3][r] + bias[3]);
                    float ct = tanh_fast  (bf2f(ybr[4 * 16 + lm]) + acc[tb][4][r] + bias[4]);
                    float wcs = bf2f(ybr[5 * 16 + lm]);
                    float cn = i_ * ct + f_ * creg[tb][r];
                    creg[tb][r] = cn;
                    float hn = o_ * tanh_fast(cn) + oc * wcs;
                    hnv[tb][r] = hn;
                    hbf[tb][r] = f2bf(hn);
                }
            }
            // publish h: pair adjacent cols via shfl, even-lm lanes store u32 sc1
            #pragma unroll
            for (int tb = 0; tb < 2; ++tb)
                #pragma unroll
                for (int r = 0; r < 4; ++r) {
                    int brow = p * 32 + tb * 16 + lq * 4 + r;
                    unsigned other = (unsigned)__shfl_xor((int)hbf[tb][r], 1);
                    if ((lm & 1) == 0) {
                        unsigned w = (hbf[tb][r] & 0xFFFFu) | (other << 16);
                        __hip_atomic_store(hnx + (size_t)(bk * 64 + brow) * 8 + (lm >> 1), w,
                                           __ATOMIC_RELAXED, __HIP_MEMORY_SCOPE_AGENT);
                    }
                }
            asm volatile("s_waitcnt vmcnt(0)" ::: "memory");
            if (lane == 0 && t + 1 < T_STEPS)
                __hip_atomic_store(flags + (bk * 2 + p) * 32, t + 1,
                                   __ATOMIC_RELAXED, __HIP_MEMORY_SCOPE_AGENT);
            // out stores: off the critical path (after flag)
            #pragma unroll
            for (int tb = 0; tb < 2; ++tb)
                #pragma unroll
                for (int r = 0; r < 4; ++r) {
                    int brow = p * 32 + tb * 16 + lq * 4 + r;
                    out[((size_t)t * 64 + brow) * 512 + m] = hnv[tb][r];
                    if (t == T_STEPS - 1)
                        out[OUT_N + 32768 + (size_t)brow * 512 + m] = hnv[tb][r];   // h_fin
                }
        } else if (t + 1 < T_STEPS) {
            // (3) q==1 waves prefetch y slab for t+1 into buf[cur^1] while q==0 runs epilogue
            const unsigned short* slab = ytile + (size_t)((t + 1) * NBLK2 + bk) * 6144;
            unsigned short* lbase = &ybuf[cur ^ 1][0];
            #pragma unroll
            for (int i = 0; i < 6; ++i) {
                int ch = p * 6 + i;
                __builtin_amdgcn_global_load_lds(
                    (const __attribute__((address_space(1))) unsigned int*)(slab + ch * 512 + lane * 8),
                    (__attribute__((address_space(3))) unsigned int*)(lbase + ch * 512), 16, 0, 0);
            }
        }
    }

    // c_fin
    if (q == 0) {
        #pragma unroll
        for (int tb = 0; tb < 2; ++tb)
            #pragma unroll
            for (int r = 0; r < 4; ++r)
                out[OUT_N + (size_t)(p * 32 + tb * 16 + lq * 4 + r) * 512 + m] = creg[tb][r];
    }
}

// ---------------- launch ----------------

extern "C" void kernel_launch(void* const* d_in, const int* in_sizes, int n_in,
                              void* d_out, int out_size, void* d_ws, size_t ws_size,
                              hipStream_t stream) {
    const float* inputs = (const float*)d_in[0];
    const float* emb_s  = (const float*)d_in[1];
    const float* c0     = (const float*)d_in[2];
    const float* h0     = (const float*)d_in[3];
    const float* W_ioux = (const float*)d_in[4];  const float* b_ioux = (const float*)d_in[5];
    const float* W_iouh = (const float*)d_in[6];  const float* b_iouh = (const float*)d_in[7];
    const float* W_ious = (const float*)d_in[8];  const float* b_ious = (const float*)d_in[9];
    const float* W_fx   = (const float*)d_in[10]; const float* b_fx   = (const float*)d_in[11];
    const float* W_fh   = (const float*)d_in[12]; const float* b_fh   = (const float*)d_in[13];
    const float* W_wc   = (const float*)d_in[14]; const float* b_wc   = (const float*)d_in[15];
    float* out = (float*)d_out;

    char* ws = (char*)d_ws;
    size_t off = 0;
    auto alloc = [&](size_t bytes) -> void* {
        void* p = ws + off;
        off += (bytes + 255) & ~(size_t)255;
        return p;
    };
    unsigned short* ytile = (unsigned short*)alloc((size_t)NROWS * NBIG * 2);   // 100.7 MB
    unsigned short* xcat  = (unsigned short*)alloc((size_t)NROWS * KCAT * 2);   // 33.6 MB
    unsigned short* wbig  = (unsigned short*)alloc((size_t)NBIG * KCAT * 2);    // 6.3 MB
    float*          bbig  = (float*)alloc(NBIG * 4);
    unsigned short* w2    = (unsigned short*)alloc((size_t)W2ROWS * 512 * 2);   // 2.6 MB
    float*          b2    = (float*)alloc(W2ROWS * 4);
    unsigned short* hslab0 = (unsigned short*)alloc(B_DIM * MDIM * 2);
    unsigned short* hslab1 = (unsigned short*)alloc(B_DIM * MDIM * 2);
    int*            flags  = (int*)alloc(8192);          // 64 flags, 128B stride

    pack_xcat<<<(NROWS * KCAT + 255) / 256, 256, 0, stream>>>(inputs, emb_s, xcat);
    pack_wbig<<<(NBIG * KCAT + 255) / 256, 256, 0, stream>>>(
        W_ioux, b_ioux, W_ious, b_ious, W_fx, b_fx, W_wc, b_wc, wbig, bbig);
    pack_w2<<<(W2ROWS * 512 + 255) / 256, 256, 0, stream>>>(W_iouh, b_iouh, W_fh, b_fh, w2, b2);
    init_state<<<(B_DIM * MDIM + 255) / 256, 256, 0, stream>>>(h0, hslab0, flags);

    dim3 g1(NBIG / 128, NROWS / 128);
    gemm_big<<<g1, 256, 0, stream>>>(xcat, wbig, bbig, ytile);

    lstm_persist<<<NBLK2, 256, 0, stream>>>(ytile, w2, b2, c0, hslab0, hslab1, out, flags);
}